// Round 1
// 367.398 us; speedup vs baseline: 1.0477x; 1.0477x over previous
//
#include <hip/hip_runtime.h>
#include <hip/hip_bf16.h>
#include <cstddef>

#define NN 2000
#define CC 4
#define LL1 5000
#define LL2 1248   /* (5000-11)/4+1 */
#define LL3 207    /* (1248-11)/6+1 */
#define FSTR 208   /* feat row stride (207 + 1 zero pad) */
#define HH 512
#define EE 64000

// ---------------- device-global scratch ----------------
__device__ float g_feat[NN * FSTR];
__device__ float g_aggf[NN * FSTR];
__device__ float g_z[NN * HH];
__device__ float g_xl[NN * HH];
__device__ float g_obuf[NN * HH];
__device__ float g_dinv[NN];
__device__ float g_colsum[HH];
__device__ float g_colsq[HH];
__device__ int   g_cnt[NN];
__device__ int   g_cursor[NN];
__device__ int   g_off[NN];
__device__ int   g_bucket[EE];

// ---------------- per-node conv chain (zero_init folded into first 8 blocks) ----
#define MCH 1256
__global__ __launch_bounds__(256) void conv_chain(
    const float* __restrict__ x,
    const float* __restrict__ w1, const float* __restrict__ b1,
    const float* __restrict__ w2, const float* __restrict__ b2,
    const float* __restrict__ w3, const float* __restrict__ b3)
{
    __shared__ __align__(16) float sm[4 * MCH];
    __shared__ __align__(16) float sy[4 * LL2];

    const int tid = threadIdx.x;
    const int node = blockIdx.x;

    // folded zero-init (graph replay reuses globals; runs every call, before any
    // consumer kernel by stream order)
    if (node < 8) {
        int i = node * 256 + tid;
        if (i < NN) { g_cnt[i] = 0; g_cursor[i] = 0; }
        if (i < HH) { g_colsum[i] = 0.f; g_colsq[i] = 0.f; }
    }

    const float* xb = x + (size_t)node * (CC * LL1);

    float w1r[64], b1r[16];
#pragma unroll
    for (int i = 0; i < 64; ++i) w1r[i] = w1[i];
#pragma unroll
    for (int i = 0; i < 16; ++i) b1r[i] = b1[i];

#pragma unroll 1
    for (int c = 0; c < 4; ++c) {
        const int l0 = 1248 * c;
        for (int g4 = tid; g4 < 314; g4 += 256) {
            const int l = l0 + 4 * g4;
            float xs[4][4];
#pragma unroll
            for (int ch = 0; ch < 4; ++ch)
                *(float4*)xs[ch] = *(const float4*)(xb + ch * LL1 + l);
#pragma unroll
            for (int g = 0; g < 4; ++g) {
                float mv[4];
#pragma unroll
                for (int li = 0; li < 4; ++li) {
                    float best = -1e30f;
#pragma unroll
                    for (int j = 0; j < 4; ++j) {
                        int o = g * 4 + j;
                        float v = b1r[o] + w1r[o*4+0]*xs[0][li] + w1r[o*4+1]*xs[1][li]
                                         + w1r[o*4+2]*xs[2][li] + w1r[o*4+3]*xs[3][li];
                        best = fmaxf(best, v);
                    }
                    mv[li] = fmaxf(best, 0.f);
                }
                *(float4*)&sm[g * MCH + 4 * g4] = make_float4(mv[0], mv[1], mv[2], mv[3]);
            }
        }
        __syncthreads();

        const int T0 = 312 * c;
#pragma unroll 1
        for (int pair = 0; pair < 2; ++pair) {
            const float* wp = w2 + 88 * pair;
            float wo[88];
#pragma unroll
            for (int i = 0; i < 88; ++i) wo[i] = wp[i];
            const float bo0 = b2[2 * pair], bo1 = b2[2 * pair + 1];
            for (int T = tid; T < 312; T += 256) {
                float a0 = bo0, a1 = bo1;
#pragma unroll
                for (int i = 0; i < 4; ++i) {
                    const float* mp = sm + i * MCH + 4 * T;
                    float4 u0 = *(const float4*)mp;
                    float4 u1 = *(const float4*)(mp + 4);
                    float4 u2 = *(const float4*)(mp + 8);
                    float v[12] = {u0.x, u0.y, u0.z, u0.w,
                                   u1.x, u1.y, u1.z, u1.w,
                                   u2.x, u2.y, u2.z, u2.w};
#pragma unroll
                    for (int k = 0; k < 11; ++k) {
                        a0 += wo[i * 11 + k] * v[k];
                        a1 += wo[44 + i * 11 + k] * v[k];
                    }
                }
                sy[(2 * pair) * LL2 + T0 + T]     = fmaxf(a0, 0.f);
                sy[(2 * pair + 1) * LL2 + T0 + T] = fmaxf(a1, 0.f);
            }
        }
        __syncthreads();
    }

    if (tid < FSTR) {
        float acc = 0.f;
        if (tid < LL3) {
            acc = b3[0];
#pragma unroll
            for (int i = 0; i < 4; ++i)
#pragma unroll
                for (int k = 0; k < 11; ++k)
                    acc += w3[i * 11 + k] * sy[i * LL2 + 6 * tid + k];
            acc = fmaxf(acc, 0.f);
        }
        g_feat[(size_t)node * FSTR + tid] = acc;
    }
}

// ---------------- edge processing ----------------
__global__ void edge_count(const int* __restrict__ ei, int E) {
    int e = blockIdx.x * 256 + threadIdx.x;
    if (e < E) atomicAdd(&g_cnt[ei[E + e]], 1);
}

__global__ __launch_bounds__(256) void scan_dinv() {
    __shared__ int a[2048], b[2048];
    int tid = threadIdx.x;
    for (int i = tid; i < 2048; i += 256) a[i] = (i < NN) ? g_cnt[i] : 0;
    __syncthreads();
    int* src = a; int* dst = b;
    for (int d = 1; d < 2048; d <<= 1) {
        for (int i = tid; i < 2048; i += 256)
            dst[i] = src[i] + ((i >= d) ? src[i - d] : 0);
        __syncthreads();
        int* t = src; src = dst; dst = t;
    }
    for (int i = tid; i < NN; i += 256) {
        g_off[i] = src[i] - g_cnt[i];
        g_dinv[i] = rsqrtf(1.0f + (float)g_cnt[i]);
    }
}

__global__ void bucket_fill(const int* __restrict__ ei, int E) {
    int e = blockIdx.x * 256 + threadIdx.x;
    if (e < E) {
        int d = ei[E + e];
        int p = atomicAdd(&g_cursor[d], 1);
        g_bucket[g_off[d] + p] = ei[e];
    }
}

// ---------------- aggregate feat over graph (float4 gathers, 4 nodes/block) -------
__global__ __launch_bounds__(256) void agg_feat() {
    const int sub = threadIdx.x >> 6;
    const int lane = threadIdx.x & 63;
    const int d = blockIdx.x * 4 + sub;          // grid 500 -> d < 2000
    if (lane >= 52) return;
    const float di = g_dinv[d];
    const int nb = g_cnt[d];
    const int base = g_off[d];
    const size_t co = (size_t)lane * 4;
    float4 a = *(const float4*)(g_feat + (size_t)d * FSTR + co);
    float ax = a.x * di, ay = a.y * di, az = a.z * di, aw = a.w * di;
    int j = 0;
    for (; j + 1 < nb; j += 2) {
        int s0 = g_bucket[base + j];
        int s1 = g_bucket[base + j + 1];
        float w0 = g_dinv[s0], w1 = g_dinv[s1];
        float4 f0 = *(const float4*)(g_feat + (size_t)s0 * FSTR + co);
        float4 f1 = *(const float4*)(g_feat + (size_t)s1 * FSTR + co);
        ax += f0.x * w0 + f1.x * w1;
        ay += f0.y * w0 + f1.y * w1;
        az += f0.z * w0 + f1.z * w1;
        aw += f0.w * w0 + f1.w * w1;
    }
    if (j < nb) {
        int s = g_bucket[base + j];
        float w = g_dinv[s];
        float4 f = *(const float4*)(g_feat + (size_t)s * FSTR + co);
        ax += f.x * w; ay += f.y * w; az += f.z * w; aw += f.w * w;
    }
    *(float4*)(g_aggf + (size_t)d * FSTR + co) = make_float4(ax * di, ay * di, az * di, aw * di);
}

// ---------------- GEMM 64x64 tile, 256 thr, 4x4 micro-tile, dbuf ----------------
// z = tanh(aggf @ gcn_w + gcn_b)  [blockIdx.z==0]
// xl =      feat @ lin_w + lin_b  [blockIdx.z==1]
// LDS k-major, row stride 68 floats (=272B, 16B aligned, bank-spread).
__global__ __launch_bounds__(256) void gemm_zxl(
    const float* __restrict__ gcn_w, const float* __restrict__ gcn_b,
    const float* __restrict__ lin_w, const float* __restrict__ lin_b)
{
    __shared__ __align__(16) float As[2][16][68];
    __shared__ __align__(16) float Bs[2][16][68];
    const int tid = threadIdx.x;
    const int which = blockIdx.z;
    const float* __restrict__ A = which ? g_feat : g_aggf;
    const float* __restrict__ B = which ? lin_w : gcn_w;
    const float* __restrict__ bias = which ? lin_b : gcn_b;
    float* __restrict__ C = which ? g_xl : g_z;
    const int N0 = blockIdx.x * 64, M0 = blockIdx.y * 64;
    const int ar = tid >> 2, ak = (tid & 3) * 4;   // A loader: row ar, k ak..ak+3
    const int bk = tid >> 4, bn = (tid & 15) * 4;  // B loader: k bk, col bn..bn+3
    const int ty = tid >> 4, tx = tid & 15;        // compute: rows ty*4.., cols tx*4..
    const int rowA = M0 + ar;

    float acc[16];
#pragma unroll
    for (int i = 0; i < 16; ++i) acc[i] = 0.f;
    const float4 z4 = make_float4(0.f, 0.f, 0.f, 0.f);
    float4 rA, rB;

    rA = (rowA < NN) ? *(const float4*)(A + (size_t)rowA * FSTR + ak) : z4;
    rB = (bk < LL3) ? *(const float4*)(B + (size_t)bk * HH + N0 + bn) : z4;
    As[0][ak+0][ar] = rA.x; As[0][ak+1][ar] = rA.y;
    As[0][ak+2][ar] = rA.z; As[0][ak+3][ar] = rA.w;
    *(float4*)&Bs[0][bk][bn] = rB;
    __syncthreads();

#pragma unroll 1
    for (int kt = 0; kt < 13; ++kt) {              // 13*16 = 208 = FSTR (pad col = 0)
        const int cur = kt & 1;
        if (kt + 1 < 13) {
            const int k0 = (kt + 1) * 16;
            rA = (rowA < NN) ? *(const float4*)(A + (size_t)rowA * FSTR + k0 + ak) : z4;
            const int kb = k0 + bk;
            rB = (kb < LL3) ? *(const float4*)(B + (size_t)kb * HH + N0 + bn) : z4;
        }
#pragma unroll
        for (int k = 0; k < 16; ++k) {
            const float4 a4 = *(const float4*)&As[cur][k][ty * 4];
            const float4 b4 = *(const float4*)&Bs[cur][k][tx * 4];
            const float av[4] = {a4.x, a4.y, a4.z, a4.w};
            const float bv[4] = {b4.x, b4.y, b4.z, b4.w};
#pragma unroll
            for (int i = 0; i < 4; ++i)
#pragma unroll
                for (int j = 0; j < 4; ++j)
                    acc[i * 4 + j] += av[i] * bv[j];
        }
        if (kt + 1 < 13) {
            const int nxt = cur ^ 1;
            As[nxt][ak+0][ar] = rA.x; As[nxt][ak+1][ar] = rA.y;
            As[nxt][ak+2][ar] = rA.z; As[nxt][ak+3][ar] = rA.w;
            *(float4*)&Bs[nxt][bk][bn] = rB;
        }
        __syncthreads();
    }

    const int c0 = N0 + tx * 4;
    const float4 bb = *(const float4*)(bias + c0);
#pragma unroll
    for (int i = 0; i < 4; ++i) {
        const int r = M0 + ty * 4 + i;
        if (r < NN) {
            float4 v = make_float4(acc[i*4+0] + bb.x, acc[i*4+1] + bb.y,
                                   acc[i*4+2] + bb.z, acc[i*4+3] + bb.w);
            if (which == 0) { v.x = tanhf(v.x); v.y = tanhf(v.y); v.z = tanhf(v.z); v.w = tanhf(v.w); }
            *(float4*)(C + (size_t)r * HH + c0) = v;
        }
    }
}

// gate GEMM: gpre = z @ gate_w + gate_b, fused sigmoid-gate/residual/relu/colsums
// same 64x64 / 4x4 skeleton, K = 512.
__global__ __launch_bounds__(256) void gemm_gate(
    const float* __restrict__ gate_w, const float* __restrict__ gate_b)
{
    __shared__ __align__(16) float As[2][16][68];
    __shared__ __align__(16) float Bs[2][16][68];
    __shared__ float rs[64], rq[64];
    const int tid = threadIdx.x;
    const float* __restrict__ A = g_z;
    const int N0 = blockIdx.x * 64, M0 = blockIdx.y * 64;
    const int ar = tid >> 2, ak = (tid & 3) * 4;
    const int bk = tid >> 4, bn = (tid & 15) * 4;
    const int ty = tid >> 4, tx = tid & 15;
    const int rowA = M0 + ar;

    float acc[16];
#pragma unroll
    for (int i = 0; i < 16; ++i) acc[i] = 0.f;
    const float4 z4 = make_float4(0.f, 0.f, 0.f, 0.f);
    float4 rA, rB;

    rA = (rowA < NN) ? *(const float4*)(A + (size_t)rowA * HH + ak) : z4;
    rB = *(const float4*)(gate_w + (size_t)bk * HH + N0 + bn);
    As[0][ak+0][ar] = rA.x; As[0][ak+1][ar] = rA.y;
    As[0][ak+2][ar] = rA.z; As[0][ak+3][ar] = rA.w;
    *(float4*)&Bs[0][bk][bn] = rB;
    __syncthreads();

#pragma unroll 1
    for (int kt = 0; kt < 32; ++kt) {              // 32*16 = 512 = HH
        const int cur = kt & 1;
        if (kt + 1 < 32) {
            const int k0 = (kt + 1) * 16;
            rA = (rowA < NN) ? *(const float4*)(A + (size_t)rowA * HH + k0 + ak) : z4;
            rB = *(const float4*)(gate_w + (size_t)(k0 + bk) * HH + N0 + bn);
        }
#pragma unroll
        for (int k = 0; k < 16; ++k) {
            const float4 a4 = *(const float4*)&As[cur][k][ty * 4];
            const float4 b4 = *(const float4*)&Bs[cur][k][tx * 4];
            const float av[4] = {a4.x, a4.y, a4.z, a4.w};
            const float bv[4] = {b4.x, b4.y, b4.z, b4.w};
#pragma unroll
            for (int i = 0; i < 4; ++i)
#pragma unroll
                for (int j = 0; j < 4; ++j)
                    acc[i * 4 + j] += av[i] * bv[j];
        }
        if (kt + 1 < 32) {
            const int nxt = cur ^ 1;
            As[nxt][ak+0][ar] = rA.x; As[nxt][ak+1][ar] = rA.y;
            As[nxt][ak+2][ar] = rA.z; As[nxt][ak+3][ar] = rA.w;
            *(float4*)&Bs[nxt][bk][bn] = rB;
        }
        __syncthreads();
    }

    const int c0 = N0 + tx * 4;
    const float4 bb = *(const float4*)(gate_b + c0);
    float cs[4] = {0.f, 0.f, 0.f, 0.f}, cq[4] = {0.f, 0.f, 0.f, 0.f};
#pragma unroll
    for (int i = 0; i < 4; ++i) {
        const int r = M0 + ty * 4 + i;
        if (r < NN) {
            const float4 xv = *(const float4*)(g_xl + (size_t)r * HH + c0);
            const float4 zv = *(const float4*)(g_z + (size_t)r * HH + c0);
            const float pre[4] = {acc[i*4+0] + bb.x, acc[i*4+1] + bb.y,
                                  acc[i*4+2] + bb.z, acc[i*4+3] + bb.w};
            const float xa[4] = {xv.x, xv.y, xv.z, xv.w};
            const float za[4] = {zv.x, zv.y, zv.z, zv.w};
            float va[4];
#pragma unroll
            for (int j = 0; j < 4; ++j) {
                float g = 1.f / (1.f + __expf(-pre[j]));
                float v = fmaxf((1.f - g) * xa[j] + g * za[j], 0.f);
                va[j] = v; cs[j] += v; cq[j] += v * v;
            }
            *(float4*)(g_obuf + (size_t)r * HH + c0) = make_float4(va[0], va[1], va[2], va[3]);
        }
    }
    if (tid < 64) { rs[tid] = 0.f; rq[tid] = 0.f; }
    __syncthreads();
#pragma unroll
    for (int j = 0; j < 4; ++j) {
        atomicAdd(&rs[tx * 4 + j], cs[j]);
        atomicAdd(&rq[tx * 4 + j], cq[j]);
    }
    __syncthreads();
    if (tid < 64) {
        atomicAdd(&g_colsum[N0 + tid], rs[tid]);
        atomicAdd(&g_colsq[N0 + tid], rq[tid]);
    }
}

// ---------------- BN apply with inline stats ----------------
__global__ __launch_bounds__(256) void bn_apply(const float* __restrict__ gamma,
                                                const float* __restrict__ beta,
                                                float* __restrict__ out) {
    int i = blockIdx.x * 256 + threadIdx.x;  // exactly NN*HH
    int c = i & (HH - 1);
    float mean = g_colsum[c] * (1.f / (float)NN);
    float var = g_colsq[c] * (1.f / (float)NN) - mean * mean;
    float s = rsqrtf(var + 1e-5f) * gamma[c];
    out[i] = g_obuf[i] * s + (beta[c] - mean * s);
}

// ---------------- launch ----------------
extern "C" void kernel_launch(void* const* d_in, const int* in_sizes, int n_in,
                              void* d_out, int out_size, void* d_ws, size_t ws_size,
                              hipStream_t stream) {
    (void)d_ws; (void)ws_size; (void)n_in; (void)out_size;
    const float* x      = (const float*)d_in[0];
    const int*   ei     = (const int*)d_in[1];
    const float* w1     = (const float*)d_in[2];
    const float* b1     = (const float*)d_in[3];
    const float* w2     = (const float*)d_in[4];
    const float* b2     = (const float*)d_in[5];
    const float* w3     = (const float*)d_in[6];
    const float* b3     = (const float*)d_in[7];
    const float* gcn_w  = (const float*)d_in[8];
    const float* gcn_b  = (const float*)d_in[9];
    const float* lin_w  = (const float*)d_in[10];
    const float* lin_b  = (const float*)d_in[11];
    const float* gate_w = (const float*)d_in[12];
    const float* gate_b = (const float*)d_in[13];
    const float* bn_g   = (const float*)d_in[14];
    const float* bn_b   = (const float*)d_in[15];
    float* out = (float*)d_out;
    const int E = in_sizes[1] / 2;

    conv_chain<<<NN, 256, 0, stream>>>(x, w1, b1, w2, b2, w3, b3);
    edge_count<<<(E + 255) / 256, 256, 0, stream>>>(ei, E);
    scan_dinv<<<1, 256, 0, stream>>>();
    bucket_fill<<<(E + 255) / 256, 256, 0, stream>>>(ei, E);
    agg_feat<<<NN / 4, 256, 0, stream>>>();

    gemm_zxl<<<dim3(HH / 64, (NN + 63) / 64, 2), 256, 0, stream>>>(gcn_w, gcn_b, lin_w, lin_b);
    gemm_gate<<<dim3(HH / 64, (NN + 63) / 64), 256, 0, stream>>>(gate_w, gate_b);

    bn_apply<<<(NN * HH) / 256, 256, 0, stream>>>(bn_g, bn_b, out);
}